// Round 6
// baseline (148.434 us; speedup 1.0000x reference)
//
#include <hip/hip_runtime.h>
#include <cstdint>
#include <cstddef>

#define B_ 2
#define N_ 2048
#define C_ 256
#define H_ 64
#define W_ 176
#define TW 16
#define NTX 11                    // 176/16 tiles per row
#define NYB 32                    // 2-row bands
#define NTILES2 (B_*NYB*NTX)      // 704 tiles (16px x 2row)
#define NSUB 8                    // per-tile counter/list shards
#define SUBCAP 256                // per-shard list cap
#define FS 40                     // feats_t / gw_t row stride (ushort) = 80 B
#define CSTRIDE 16                // counters padded to 1 per 64B line
#define SAB 264                   // bf16 activation LDS stride (ushorts): 528B row, 2-way-free banks

typedef unsigned short ushort_t;
typedef short bf16x8 __attribute__((ext_vector_type(8)));
typedef float f32x4  __attribute__((ext_vector_type(4)));

__device__ __forceinline__ short f2bf(float f)   // RNE fp32->bf16
{
    unsigned u = __float_as_uint(f);
    return (short)((u + 0x7FFFu + ((u >> 16) & 1u)) >> 16);
}

// ---------------------------------------------------------------------------
// prep: zero tile counters + fp32->bf16 transposed weight convert.
// ---------------------------------------------------------------------------
__global__ __launch_bounds__(256)
void prep_kernel(const float* __restrict__ w3f, const float* __restrict__ fw1f,
                 const float* __restrict__ fw2f,
                 short* __restrict__ wt3, short* __restrict__ wt4,
                 short* __restrict__ wt5, int* __restrict__ counts)
{
    const int gid = blockIdx.x * 256 + threadIdx.x;
    for (int c = gid; c < NTILES2 * NSUB * CSTRIDE; c += 65536) counts[c] = 0;
    for (int e = gid; e < 163840; e += 65536) {
        if (e < 32768) {                      // w3f[k][n] (128x256) -> wt3[n*128+k]
            const int k = e >> 8, n = e & 255;
            wt3[n * 128 + k] = f2bf(w3f[e]);
        } else if (e < 98304) {               // fw1f[k][n] (256x256) -> wt4[n*256+k]
            const int e2 = e - 32768;
            const int k = e2 >> 8, n = e2 & 255;
            wt4[n * 256 + k] = f2bf(fw1f[e2]);
        } else {                              // fw2f[k][n] (256x256) -> wt5[n*256+k]
            const int e2 = e - 98304;
            const int k = e2 >> 8, n = e2 & 255;
            wt5[n * 256 + k] = f2bf(fw2f[e2]);
        }
    }
}

// ---------------------------------------------------------------------------
// MFMA accumulate on bf16 LDS activations (converted once at write time).
// Inner loop: 1 ds_read_b128 + 2 MFMA per ks. Weights preloaded to regs.
// ---------------------------------------------------------------------------
template<int K>
__device__ __forceinline__ void mfma_accB(const short* __restrict__ wt,
                                          const ushort_t* actB, f32x4 (&acc)[2],
                                          int wv_, int quad, int ln15)
{
    bf16x8 wreg[K / 16];
#pragma unroll
    for (int ks = 0; ks < K / 32; ++ks) {
        const int kb = ks * 32 + quad * 8;
#pragma unroll
        for (int tt = 0; tt < 2; ++tt) {
            const int n0 = (wv_ * 2 + tt) * 16;
            wreg[ks * 2 + tt] = *(const bf16x8*)&wt[(size_t)(n0 + ln15) * K + kb];
        }
    }
#pragma unroll
    for (int ks = 0; ks < K / 32; ++ks) {
        const int kb = ks * 32 + quad * 8;
        const bf16x8 af = *(const bf16x8*)&actB[ln15 * SAB + kb];
#pragma unroll
        for (int tt = 0; tt < 2; ++tt)
            acc[tt] = __builtin_amdgcn_mfma_f32_16x16x32_bf16(af, wreg[ks * 2 + tt],
                                                              acc[tt], 0, 0, 0);
    }
}

// ---------------------------------------------------------------------------
// Fused MLP + param/bin, 512 threads. Activations held bf16 in LDS.
// ---------------------------------------------------------------------------
__global__ __launch_bounds__(512, 4)
void pb_mlp_kernel(const float* __restrict__ g, const float* __restrict__ intr,
                   const float* __restrict__ w1, const float* __restrict__ b1,
                   const float* __restrict__ w2, const float* __restrict__ b2,
                   const short* __restrict__ wt3, const float* __restrict__ b3,
                   const short* __restrict__ wt4, const float* __restrict__ fb1,
                   const short* __restrict__ wt5, const float* __restrict__ fb2,
                   ushort_t* __restrict__ ftb,
                   float* __restrict__ pp, int* __restrict__ counts,
                   ushort_t* __restrict__ lists)
{
    __shared__ __align__(16) float   s32a[16 * 16];    // g input (14 cols)
    __shared__ __align__(16) float   s32b[16 * 68];    // L1 out fp32 (64 cols)
    __shared__ __align__(16) ushort_t bA[16 * SAB];    // L2 out / L4 out (bf16)
    __shared__ __align__(16) ushort_t bB[16 * SAB];    // L3 out (bf16)
    const int tid = threadIdx.x;

    if (blockIdx.x < 256) {
        const int row0 = blockIdx.x * 16;
        const int lane = tid & 63;
        const int wv_  = tid >> 6;
        const int quad = lane >> 4;
        const int ln15 = lane & 15;

        if (tid < 224) {
            const int k = tid / 16, m = tid % 16;
            s32a[m * 16 + k] = g[(size_t)(row0 + m) * 14 + k];
        }
        __syncthreads();

        {   // L1: 14 -> 64, relu (fp32 out)
            const int col = tid & 63;
            const int m0  = (tid >> 6) * 2;
            float acc[2];
            const float bv = b1[col];
            acc[0] = bv; acc[1] = bv;
#pragma unroll
            for (int k = 0; k < 14; ++k) {
                const float wv = w1[k * 64 + col];
                acc[0] = fmaf(s32a[(m0 + 0) * 16 + k], wv, acc[0]);
                acc[1] = fmaf(s32a[(m0 + 1) * 16 + k], wv, acc[1]);
            }
            s32b[(m0 + 0) * 68 + col] = fmaxf(acc[0], 0.f);
            s32b[(m0 + 1) * 68 + col] = fmaxf(acc[1], 0.f);
        }
        __syncthreads();

        {   // L2: 64 -> 128, relu -> bf16 (converted once at write)
            const int col = tid & 127;
            const int m0  = (tid >> 7) * 4;
            float acc[4];
            const float bv = b2[col];
#pragma unroll
            for (int r = 0; r < 4; ++r) acc[r] = bv;
#pragma unroll 4
            for (int kq = 0; kq < 16; ++kq) {
                float wv[4];
#pragma unroll
                for (int jj = 0; jj < 4; ++jj) wv[jj] = w2[(4 * kq + jj) * 128 + col];
#pragma unroll
                for (int r = 0; r < 4; ++r) {
                    const float4 a4 = *(const float4*)&s32b[(m0 + r) * 68 + 4 * kq];
                    acc[r] = fmaf(a4.x, wv[0], acc[r]);
                    acc[r] = fmaf(a4.y, wv[1], acc[r]);
                    acc[r] = fmaf(a4.z, wv[2], acc[r]);
                    acc[r] = fmaf(a4.w, wv[3], acc[r]);
                }
            }
#pragma unroll
            for (int r = 0; r < 4; ++r)
                bA[(m0 + r) * SAB + col] = (ushort_t)f2bf(fmaxf(acc[r], 0.f));
        }
        __syncthreads();

        {   // L3: 128 -> 256 MFMA, out -> bB (bf16)
            f32x4 acc[2] = {{0,0,0,0},{0,0,0,0}};
            mfma_accB<128>(wt3, bA, acc, wv_, quad, ln15);
#pragma unroll
            for (int tt = 0; tt < 2; ++tt) {
                const int n = (wv_ * 2 + tt) * 16 + ln15;
                const float bv = b3[n];
#pragma unroll
                for (int r = 0; r < 4; ++r)
                    bB[(quad * 4 + r) * SAB + n] = (ushort_t)f2bf(acc[tt][r] + bv);
            }
        }
        __syncthreads();

        {   // L4: 256 -> 256 MFMA, relu, out -> bA (bf16)
            f32x4 acc[2] = {{0,0,0,0},{0,0,0,0}};
            mfma_accB<256>(wt4, bB, acc, wv_, quad, ln15);
#pragma unroll
            for (int tt = 0; tt < 2; ++tt) {
                const int n = (wv_ * 2 + tt) * 16 + ln15;
                const float bv = fb1[n];
#pragma unroll
                for (int r = 0; r < 4; ++r)
                    bA[(quad * 4 + r) * SAB + n] =
                        (ushort_t)f2bf(fmaxf(acc[tt][r] + bv, 0.f));
            }
        }
        __syncthreads();

        {   // L5: 256 -> 256 MFMA -> global bf16
            f32x4 acc[2] = {{0,0,0,0},{0,0,0,0}};
            mfma_accB<256>(wt5, bA, acc, wv_, quad, ln15);
#pragma unroll
            for (int tt = 0; tt < 2; ++tt) {
                const int n = (wv_ * 2 + tt) * 16 + ln15;
                const float bv = fb2[n];
#pragma unroll
                for (int r = 0; r < 4; ++r)
                    ftb[(size_t)(row0 + quad * 4 + r) * 256 + n] =
                        (ushort_t)f2bf(acc[tt][r] + bv);
            }
        }
        return;
    }

    // ================= param + bin role (2-row bands) =================
    const int sub = (blockIdx.x - 256) & (NSUB - 1);
    const int i = (blockIdx.x - 256) * 16 + (tid >> 5);
    const int j = tid & 31;
    const float* gi = g + (size_t)i * 14;
    const float x = gi[0], y = gi[1], z = gi[2];
    const float s5 = gi[5], s6 = gi[6], wv = gi[12];
    const float k00 = intr[0], k01 = intr[1], k02 = intr[2];
    const float k10 = intr[3], k11 = intr[4], k12 = intr[5];
    const float k20 = intr[6], k21 = intr[7], k22 = intr[8];
    const float projx = k00 * x + k01 * y + k02 * z;
    const float projy = k10 * x + k11 * y + k12 * z;
    const float projz = k20 * x + k21 * y + k22 * z;
    const float inv = 1.f / (projz + 1e-6f);
    const float scale_x = (float)W_ / k02 * 0.5f;
    const float scale_y = (float)H_ / k12 * 0.5f;
    const float px = projx * inv * scale_x;
    const float py = projy * inv * scale_y;
    const bool valid = z > 0.1f;
    const bool inb = (px >= 0.f) && (px < (float)W_) && (py >= 0.f) && (py < (float)H_);
    const bool mask = valid && inb;
    const float sx = fmaxf(s5 * scale_x, 1.f);
    const float sy = fmaxf(s6 * scale_y, 1.f);
    if (j == 0) {
        float4* o = (float4*)(pp + (size_t)i * 8);
        o[0] = make_float4(px, py, 1.f / sx, 1.f / sy);
        o[1] = make_float4(wv, 0.5f * (sx + sy), 0.f, 0.f);
    }
    if (!mask) return;
    const float rx = 3.f * sx, ry = 3.f * sy;
    const int ymin = max(0, (int)floorf(py - ry));
    const int ymax = min(H_ - 1, (int)ceilf(py + ry));
    const int bmin = ymin >> 1, bmax = ymax >> 1;
    const int band = bmin + j;
    if (band > bmax) return;
    const int tmin = max(0, (int)floorf((px - rx - (float)(TW - 1)) * (1.f / TW)));
    const int tmax = min(NTX - 1, (int)ceilf((px + rx) * (1.f / TW)));
    const int b = i / N_, n = i - b * N_;
    for (int t = tmin; t <= tmax; ++t) {
        const int tile = (b * NYB + band) * NTX + t;
        const int slot = atomicAdd(&counts[(tile * NSUB + sub) * CSTRIDE], 1);
        if (slot < SUBCAP)
            lists[((size_t)tile * NSUB + sub) * SUBCAP + slot] = (ushort_t)n;
    }
}

// ---------------------------------------------------------------------------
// Splat, 512 threads / 8 waves, register-pipelined prefetch:
//   pp params distance-1 (refilled right after phase A),
//   ftb rows distance-2 (two reg sets, refilled right after the barrier).
// Cuts the hot block's per-chunk L2 stalls off the serial critical path.
// ---------------------------------------------------------------------------
__global__ __launch_bounds__(512, 4)
void splat_kernel(const float* __restrict__ pp, const ushort_t* __restrict__ lists,
                  const int* __restrict__ counts, const ushort_t* __restrict__ ftb,
                  float* __restrict__ out)
{
    __shared__ __align__(16) ushort_t feats_t[2][256 * FS];  // 2 x 20 KB
    __shared__ __align__(16) ushort_t gw_t[2][32 * FS];      // 2 x 2.5 KB
    __shared__ __align__(16) ushort_t list_s[NSUB * SUBCAP]; // 4 KB

    const int tid = threadIdx.x;
    // center-first tile decode
    const int qb = blockIdx.x;
    const int b  = qb & 1;
    const int t_ = qb >> 1;
    const int yr = t_ / NTX, xr = t_ % NTX;
    const int yh = (yr + 1) >> 1;
    const int yb = (yr & 1) ? (16 - yh) : (16 + yh);
    const int xh = (xr + 1) >> 1;
    const int txi = (xr & 1) ? (5 - xh) : (5 + xh);
    const int tb  = (b * NYB + yb) * NTX + txi;
    const int y0 = yb * 2, x0 = txi * TW;

    // ---- gather sub-lists -> contiguous LDS list (counts prefetched) ----
    int cs[NSUB];
#pragma unroll
    for (int s = 0; s < NSUB; ++s)
        cs[s] = min(counts[(tb * NSUB + s) * CSTRIDE], SUBCAP);
    int off[NSUB];
    int tot = 0;
#pragma unroll
    for (int s = 0; s < NSUB; ++s) { off[s] = tot; tot += cs[s]; }
#pragma unroll
    for (int s = 0; s < NSUB; ++s) {
        const ushort_t* src = lists + ((size_t)tb * NSUB + s) * SUBCAP;
        if (tid < cs[s]) list_s[off[s] + tid] = src[tid];
    }
    __syncthreads();
    const int cnt = tot;

    const int gs   = tid >> 5;            // phase A gaussian sub-slot (0..15)
    const int px32 = tid & 31;            // phase A pixel (row*16+x)
    const float fy = (float)(y0 + (px32 >> 4));
    const float fx = (float)(x0 + (px32 & 15));
    const int chg = tid >> 4;             // stage: ch group (0..31), 8 ch each
    const int qp  = tid & 15;             // stage: q pair (0..15)
    const int bN = b * N_;
    const int lane = tid & 63;
    const int wv_  = tid >> 6;            // 0..7
    const int quad = lane >> 4;
    const int ln15 = lane & 15;

    f32x4 acc[2][2];
#pragma unroll
    for (int mt = 0; mt < 2; ++mt)
#pragma unroll
        for (int nt = 0; nt < 2; ++nt) acc[mt][nt] = (f32x4){0.f, 0.f, 0.f, 0.f};
    float densp = 0.f, uncp = 0.f;

    uint4 fa[2], fb[2];                   // ftb prefetch, set = chunk&1 (distance 2)
    float4 pe0[2], pe1[2];                // pv params prefetch (distance 1)
    const int nchunks = (cnt + 31) >> 5;

    if (cnt > 0) {
        const float4* pv = (const float4*)pp;
        // ---- prologue: prefetch ftb chunks 0,1 and pv chunk 0 ----
        {
            const int n0 = list_s[min(2 * qp, cnt - 1)];
            const int n1 = list_s[min(2 * qp + 1, cnt - 1)];
            fa[0] = *(const uint4*)(ftb + ((size_t)(bN + n0) << 8) + chg * 8);
            fb[0] = *(const uint4*)(ftb + ((size_t)(bN + n1) << 8) + chg * 8);
        }
        if (nchunks > 1) {
            const int q0 = 32 + 2 * qp;
            const int n0 = list_s[min(q0, cnt - 1)];
            const int n1 = list_s[min(q0 + 1, cnt - 1)];
            fa[1] = *(const uint4*)(ftb + ((size_t)(bN + n0) << 8) + chg * 8);
            fb[1] = *(const uint4*)(ftb + ((size_t)(bN + n1) << 8) + chg * 8);
        }
#pragma unroll
        for (int jj = 0; jj < 2; ++jj) {
            const int n = list_s[min(16 * jj + gs, cnt - 1)];
            pe0[jj] = pv[(size_t)(bN + n) * 2 + 0];
            pe1[jj] = pv[(size_t)(bN + n) * 2 + 1];
        }

        for (int c = 0; c < nchunks; ++c) {
            const int buf = c & 1;
            // ---- phase A: 2 gw per thread from preloaded params ----
#pragma unroll
            for (int jj = 0; jj < 2; ++jj) {
                const int q = 16 * jj + gs;
                const int qi = c * 32 + q;
                const float4 e0 = pe0[jj];
                const float4 e1 = pe1[jj];
                const float dyn = (fy - e0.y) * e0.w;
                const float dxn = (fx - e0.x) * e0.z;
                const float dist = dyn * dyn + dxn * dxn;
                float gv = 0.f;
                if (dist < 9.f) gv = __expf(-0.5f * dist) * e1.x;
                if (qi >= cnt) gv = 0.f;
                gw_t[buf][px32 * FS + q] = (ushort_t)f2bf(gv);
                densp += gv;
                uncp  += gv * e1.y;
            }
            // ---- refill pv params for chunk c+1 (covered by stage+bar+B) ----
            if (c + 1 < nchunks) {
#pragma unroll
                for (int jj = 0; jj < 2; ++jj) {
                    const int qi = (c + 1) * 32 + 16 * jj + gs;
                    const int n = list_s[min(qi, cnt - 1)];
                    pe0[jj] = pv[(size_t)(bN + n) * 2 + 0];
                    pe1[jj] = pv[(size_t)(bN + n) * 2 + 1];
                }
            }
            // ---- stage: reg set (c&1) -> feats_t[buf][ch][k] ----
            {
                uint* dst = (uint*)&feats_t[buf][0];
                const uint4 ua = fa[buf], ub = fb[buf];
#pragma unroll
                for (int jj = 0; jj < 4; ++jj) {
                    const uint u0 = (&ua.x)[jj], v0 = (&ub.x)[jj];
                    const int ch = chg * 8 + 2 * jj;
                    dst[ch * (FS / 2) + qp]       = (u0 & 0xffffu) | (v0 << 16);
                    dst[(ch + 1) * (FS / 2) + qp] = (u0 >> 16) | (v0 & 0xffff0000u);
                }
            }
            __syncthreads();
            // ---- refill ftb reg set for chunk c+2 (2 chunks of cover) ----
            if (c + 2 < nchunks) {
                const int q0 = (c + 2) * 32 + 2 * qp;
                const int n0 = list_s[min(q0, cnt - 1)];
                const int n1 = list_s[min(q0 + 1, cnt - 1)];
                fa[buf] = *(const uint4*)(ftb + ((size_t)(bN + n0) << 8) + chg * 8);
                fb[buf] = *(const uint4*)(ftb + ((size_t)(bN + n1) << 8) + chg * 8);
            }
            // ---- phase B: 4 MFMA per wave ----
            bf16x8 af[2];
#pragma unroll
            for (int mt = 0; mt < 2; ++mt)
                af[mt] = *(const bf16x8*)&gw_t[buf][(mt * 16 + ln15) * FS + quad * 8];
#pragma unroll
            for (int nt = 0; nt < 2; ++nt) {
                const int ch0 = wv_ * 32 + nt * 16;
                const bf16x8 bfv = *(const bf16x8*)&feats_t[buf][(ch0 + ln15) * FS + quad * 8];
                acc[0][nt] = __builtin_amdgcn_mfma_f32_16x16x32_bf16(af[0], bfv, acc[0][nt], 0, 0, 0);
                acc[1][nt] = __builtin_amdgcn_mfma_f32_16x16x32_bf16(af[1], bfv, acc[1][nt], 0, 0, 0);
            }
        }
    }

    // ---- density / uncertainty reduction over 16 gs-groups ----
    __syncthreads();
    float* red_d = (float*)&feats_t[0][0];   // 16 x 36
    float* red_u = red_d + 16 * 36;
    red_d[gs * 36 + px32] = densp;
    red_u[gs * 36 + px32] = uncp;
    __syncthreads();
    for (int s = 8; s > 0; s >>= 1) {
        if (gs < s) {
            red_d[gs * 36 + px32] += red_d[(gs + s) * 36 + px32];
            red_u[gs * 36 + px32] += red_u[(gs + s) * 36 + px32];
        }
        __syncthreads();
    }

    if (tid < 32) {
        const int yy = y0 + (tid >> 4), xx = x0 + (tid & 15);
        const size_t pix = ((size_t)b * H_ + yy) * W_ + xx;
        float* unc_o = out + (size_t)B_ * C_ * H_ * W_;
        float* den_o = unc_o + (size_t)B_ * H_ * W_;
        const float d = fmaxf(red_d[tid], 1e-6f);
        unc_o[pix] = red_u[tid] / d;
        den_o[pix] = d;
    }

    // ---- feature stores: lane = ch (ln15), 4 consecutive x per acc ----
#pragma unroll
    for (int mt = 0; mt < 2; ++mt) {
        const int pxb = mt * 16 + quad * 4;
        float rinv[4];
#pragma unroll
        for (int r = 0; r < 4; ++r)
            rinv[r] = 1.f / fmaxf(red_d[pxb + r], 1e-6f);
        const int yy = y0 + mt;
#pragma unroll
        for (int nt = 0; nt < 2; ++nt) {
            const int ch = wv_ * 32 + nt * 16 + ln15;
            float4 v;
            v.x = acc[mt][nt][0] * rinv[0];
            v.y = acc[mt][nt][1] * rinv[1];
            v.z = acc[mt][nt][2] * rinv[2];
            v.w = acc[mt][nt][3] * rinv[3];
            *(float4*)(out + (((size_t)b * C_ + ch) * H_ + yy) * W_
                       + x0 + quad * 4) = v;
        }
    }
}

// ---------------------------------------------------------------------------
extern "C" void kernel_launch(void* const* d_in, const int* in_sizes, int n_in,
                              void* d_out, int out_size, void* d_ws, size_t ws_size,
                              hipStream_t stream)
{
    const float* g    = (const float*)d_in[0];
    const float* intr = (const float*)d_in[1];
    const float* w1   = (const float*)d_in[2];
    const float* b1   = (const float*)d_in[3];
    const float* w2   = (const float*)d_in[4];
    const float* b2   = (const float*)d_in[5];
    const float* w3   = (const float*)d_in[6];
    const float* b3   = (const float*)d_in[7];
    const float* fw1  = (const float*)d_in[8];
    const float* fb1  = (const float*)d_in[9];
    const float* fw2  = (const float*)d_in[10];
    const float* fb2  = (const float*)d_in[11];

    char* base = (char*)d_ws;
    const int rows = B_ * N_;                                // 4096
    ushort_t* ftb = (ushort_t*)base;                         // 2 MB bf16 [row][ch]
    float* pp     = (float*)(base + (size_t)rows * C_ * 2);  // 128 KB
    int*   counts = (int*)(pp + (size_t)8 * rows);           // 704*8 counters, 64B apart
    ushort_t* lists = (ushort_t*)(counts + NTILES2 * NSUB * CSTRIDE); // 2.9 MB
    short* wt3    = (short*)(lists + (size_t)NTILES2 * NSUB * SUBCAP);
    short* wt4    = wt3 + 128 * 256;
    short* wt5    = wt4 + 256 * 256;

    prep_kernel<<<dim3(256), dim3(256), 0, stream>>>(w3, fw1, fw2, wt3, wt4, wt5, counts);
    pb_mlp_kernel<<<dim3(512), dim3(512), 0, stream>>>(
        g, intr, w1, b1, w2, b2, wt3, b3, wt4, fb1, wt5, fb2, ftb, pp, counts, lists);
    splat_kernel<<<dim3(NTILES2), dim3(512), 0, stream>>>(pp, lists, counts, ftb, (float*)d_out);
}

// Round 7
// 133.347 us; speedup vs baseline: 1.1131x; 1.1131x over previous
//
#include <hip/hip_runtime.h>
#include <cstdint>
#include <cstddef>

#define B_ 2
#define N_ 2048
#define C_ 256
#define H_ 64
#define W_ 176
#define TW 16
#define NTX 11                    // 176/16 tiles per row
#define NYB 32                    // 2-row bands
#define NTILES2 (B_*NYB*NTX)      // 704 tiles (16px x 2row)
#define NSUB 8                    // per-tile counter/list shards
#define SUBCAP 256                // per-shard list cap
#define FS 40                     // feats_t / gw_t row stride (ushort) = 80 B
#define CSTRIDE 16                // counters padded to 1 per 64B line
#define SAB 264                   // bf16 activation LDS stride (ushorts)

typedef unsigned short ushort_t;
typedef short bf16x8 __attribute__((ext_vector_type(8)));
typedef float f32x4  __attribute__((ext_vector_type(4)));

__device__ __forceinline__ short f2bf(float f)   // RNE fp32->bf16
{
    unsigned u = __float_as_uint(f);
    return (short)((u + 0x7FFFu + ((u >> 16) & 1u)) >> 16);
}

// ---------------------------------------------------------------------------
// prep: zero tile counters + fp32->bf16 transposed weight convert.
// ---------------------------------------------------------------------------
__global__ __launch_bounds__(256)
void prep_kernel(const float* __restrict__ w3f, const float* __restrict__ fw1f,
                 const float* __restrict__ fw2f,
                 short* __restrict__ wt3, short* __restrict__ wt4,
                 short* __restrict__ wt5, int* __restrict__ counts)
{
    const int gid = blockIdx.x * 256 + threadIdx.x;
    for (int c = gid; c < NTILES2 * NSUB * CSTRIDE; c += 65536) counts[c] = 0;
    for (int e = gid; e < 163840; e += 65536) {
        if (e < 32768) {                      // w3f[k][n] (128x256) -> wt3[n*128+k]
            const int k = e >> 8, n = e & 255;
            wt3[n * 128 + k] = f2bf(w3f[e]);
        } else if (e < 98304) {               // fw1f[k][n] (256x256) -> wt4[n*256+k]
            const int e2 = e - 32768;
            const int k = e2 >> 8, n = e2 & 255;
            wt4[n * 256 + k] = f2bf(fw1f[e2]);
        } else {                              // fw2f[k][n] (256x256) -> wt5[n*256+k]
            const int e2 = e - 98304;
            const int k = e2 >> 8, n = e2 & 255;
            wt5[n * 256 + k] = f2bf(fw2f[e2]);
        }
    }
}

// ---------------------------------------------------------------------------
// MFMA accumulate on bf16 LDS activations (converted once at write time).
// ---------------------------------------------------------------------------
template<int K>
__device__ __forceinline__ void mfma_accB(const short* __restrict__ wt,
                                          const ushort_t* actB, f32x4 (&acc)[2],
                                          int wv_, int quad, int ln15)
{
    bf16x8 wreg[K / 16];
#pragma unroll
    for (int ks = 0; ks < K / 32; ++ks) {
        const int kb = ks * 32 + quad * 8;
#pragma unroll
        for (int tt = 0; tt < 2; ++tt) {
            const int n0 = (wv_ * 2 + tt) * 16;
            wreg[ks * 2 + tt] = *(const bf16x8*)&wt[(size_t)(n0 + ln15) * K + kb];
        }
    }
#pragma unroll
    for (int ks = 0; ks < K / 32; ++ks) {
        const int kb = ks * 32 + quad * 8;
        const bf16x8 af = *(const bf16x8*)&actB[ln15 * SAB + kb];
#pragma unroll
        for (int tt = 0; tt < 2; ++tt)
            acc[tt] = __builtin_amdgcn_mfma_f32_16x16x32_bf16(af, wreg[ks * 2 + tt],
                                                              acc[tt], 0, 0, 0);
    }
}

// ---------------------------------------------------------------------------
// Fused MLP + param/bin, 512 threads. Activations held bf16 in LDS.
// ---------------------------------------------------------------------------
__global__ __launch_bounds__(512, 4)
void pb_mlp_kernel(const float* __restrict__ g, const float* __restrict__ intr,
                   const float* __restrict__ w1, const float* __restrict__ b1,
                   const float* __restrict__ w2, const float* __restrict__ b2,
                   const short* __restrict__ wt3, const float* __restrict__ b3,
                   const short* __restrict__ wt4, const float* __restrict__ fb1,
                   const short* __restrict__ wt5, const float* __restrict__ fb2,
                   ushort_t* __restrict__ ftb,
                   float* __restrict__ pp, int* __restrict__ counts,
                   ushort_t* __restrict__ lists)
{
    __shared__ __align__(16) float   s32a[16 * 16];    // g input (14 cols)
    __shared__ __align__(16) float   s32b[16 * 68];    // L1 out fp32 (64 cols)
    __shared__ __align__(16) ushort_t bA[16 * SAB];    // L2 out / L4 out (bf16)
    __shared__ __align__(16) ushort_t bB[16 * SAB];    // L3 out (bf16)
    const int tid = threadIdx.x;

    if (blockIdx.x < 256) {
        const int row0 = blockIdx.x * 16;
        const int lane = tid & 63;
        const int wv_  = tid >> 6;
        const int quad = lane >> 4;
        const int ln15 = lane & 15;

        if (tid < 224) {
            const int k = tid / 16, m = tid % 16;
            s32a[m * 16 + k] = g[(size_t)(row0 + m) * 14 + k];
        }
        __syncthreads();

        {   // L1: 14 -> 64, relu (fp32 out)
            const int col = tid & 63;
            const int m0  = (tid >> 6) * 2;
            float acc[2];
            const float bv = b1[col];
            acc[0] = bv; acc[1] = bv;
#pragma unroll
            for (int k = 0; k < 14; ++k) {
                const float wv = w1[k * 64 + col];
                acc[0] = fmaf(s32a[(m0 + 0) * 16 + k], wv, acc[0]);
                acc[1] = fmaf(s32a[(m0 + 1) * 16 + k], wv, acc[1]);
            }
            s32b[(m0 + 0) * 68 + col] = fmaxf(acc[0], 0.f);
            s32b[(m0 + 1) * 68 + col] = fmaxf(acc[1], 0.f);
        }
        __syncthreads();

        {   // L2: 64 -> 128, relu -> bf16 (converted once at write)
            const int col = tid & 127;
            const int m0  = (tid >> 7) * 4;
            float acc[4];
            const float bv = b2[col];
#pragma unroll
            for (int r = 0; r < 4; ++r) acc[r] = bv;
#pragma unroll 4
            for (int kq = 0; kq < 16; ++kq) {
                float wv[4];
#pragma unroll
                for (int jj = 0; jj < 4; ++jj) wv[jj] = w2[(4 * kq + jj) * 128 + col];
#pragma unroll
                for (int r = 0; r < 4; ++r) {
                    const float4 a4 = *(const float4*)&s32b[(m0 + r) * 68 + 4 * kq];
                    acc[r] = fmaf(a4.x, wv[0], acc[r]);
                    acc[r] = fmaf(a4.y, wv[1], acc[r]);
                    acc[r] = fmaf(a4.z, wv[2], acc[r]);
                    acc[r] = fmaf(a4.w, wv[3], acc[r]);
                }
            }
#pragma unroll
            for (int r = 0; r < 4; ++r)
                bA[(m0 + r) * SAB + col] = (ushort_t)f2bf(fmaxf(acc[r], 0.f));
        }
        __syncthreads();

        {   // L3: 128 -> 256 MFMA, out -> bB (bf16)
            f32x4 acc[2] = {{0,0,0,0},{0,0,0,0}};
            mfma_accB<128>(wt3, bA, acc, wv_, quad, ln15);
#pragma unroll
            for (int tt = 0; tt < 2; ++tt) {
                const int n = (wv_ * 2 + tt) * 16 + ln15;
                const float bv = b3[n];
#pragma unroll
                for (int r = 0; r < 4; ++r)
                    bB[(quad * 4 + r) * SAB + n] = (ushort_t)f2bf(acc[tt][r] + bv);
            }
        }
        __syncthreads();

        {   // L4: 256 -> 256 MFMA, relu, out -> bA (bf16)
            f32x4 acc[2] = {{0,0,0,0},{0,0,0,0}};
            mfma_accB<256>(wt4, bB, acc, wv_, quad, ln15);
#pragma unroll
            for (int tt = 0; tt < 2; ++tt) {
                const int n = (wv_ * 2 + tt) * 16 + ln15;
                const float bv = fb1[n];
#pragma unroll
                for (int r = 0; r < 4; ++r)
                    bA[(quad * 4 + r) * SAB + n] =
                        (ushort_t)f2bf(fmaxf(acc[tt][r] + bv, 0.f));
            }
        }
        __syncthreads();

        {   // L5: 256 -> 256 MFMA -> global bf16
            f32x4 acc[2] = {{0,0,0,0},{0,0,0,0}};
            mfma_accB<256>(wt5, bA, acc, wv_, quad, ln15);
#pragma unroll
            for (int tt = 0; tt < 2; ++tt) {
                const int n = (wv_ * 2 + tt) * 16 + ln15;
                const float bv = fb2[n];
#pragma unroll
                for (int r = 0; r < 4; ++r)
                    ftb[(size_t)(row0 + quad * 4 + r) * 256 + n] =
                        (ushort_t)f2bf(acc[tt][r] + bv);
            }
        }
        return;
    }

    // ================= param + bin role (2-row bands) =================
    const int sub = (blockIdx.x - 256) & (NSUB - 1);
    const int i = (blockIdx.x - 256) * 16 + (tid >> 5);
    const int j = tid & 31;
    const float* gi = g + (size_t)i * 14;
    const float x = gi[0], y = gi[1], z = gi[2];
    const float s5 = gi[5], s6 = gi[6], wv = gi[12];
    const float k00 = intr[0], k01 = intr[1], k02 = intr[2];
    const float k10 = intr[3], k11 = intr[4], k12 = intr[5];
    const float k20 = intr[6], k21 = intr[7], k22 = intr[8];
    const float projx = k00 * x + k01 * y + k02 * z;
    const float projy = k10 * x + k11 * y + k12 * z;
    const float projz = k20 * x + k21 * y + k22 * z;
    const float inv = 1.f / (projz + 1e-6f);
    const float scale_x = (float)W_ / k02 * 0.5f;
    const float scale_y = (float)H_ / k12 * 0.5f;
    const float px = projx * inv * scale_x;
    const float py = projy * inv * scale_y;
    const bool valid = z > 0.1f;
    const bool inb = (px >= 0.f) && (px < (float)W_) && (py >= 0.f) && (py < (float)H_);
    const bool mask = valid && inb;
    const float sx = fmaxf(s5 * scale_x, 1.f);
    const float sy = fmaxf(s6 * scale_y, 1.f);
    if (j == 0) {
        float4* o = (float4*)(pp + (size_t)i * 8);
        o[0] = make_float4(px, py, 1.f / sx, 1.f / sy);
        o[1] = make_float4(wv, 0.5f * (sx + sy), 0.f, 0.f);
    }
    if (!mask) return;
    const float rx = 3.f * sx, ry = 3.f * sy;
    const int ymin = max(0, (int)floorf(py - ry));
    const int ymax = min(H_ - 1, (int)ceilf(py + ry));
    const int bmin = ymin >> 1, bmax = ymax >> 1;
    const int band = bmin + j;
    if (band > bmax) return;
    const int tmin = max(0, (int)floorf((px - rx - (float)(TW - 1)) * (1.f / TW)));
    const int tmax = min(NTX - 1, (int)ceilf((px + rx) * (1.f / TW)));
    const int b = i / N_, n = i - b * N_;
    for (int t = tmin; t <= tmax; ++t) {
        const int tile = (b * NYB + band) * NTX + t;
        const int slot = atomicAdd(&counts[(tile * NSUB + sub) * CSTRIDE], 1);
        if (slot < SUBCAP)
            lists[((size_t)tile * NSUB + sub) * SUBCAP + slot] = (ushort_t)n;
    }
}

// ---------------------------------------------------------------------------
// Splat, 512 threads / 8 waves. Chunk loop unrolled by 2 with NAMED prefetch
// register sets (fa0/fb0 even, fa1/fb1 odd) -> all register indices are
// compile-time (no scratch). ftb prefetch distance 2, pp params distance 1.
// ---------------------------------------------------------------------------
__global__ __launch_bounds__(512)
void splat_kernel(const float* __restrict__ pp, const ushort_t* __restrict__ lists,
                  const int* __restrict__ counts, const ushort_t* __restrict__ ftb,
                  float* __restrict__ out)
{
    __shared__ __align__(16) ushort_t feats_t[2][256 * FS];  // 2 x 20 KB
    __shared__ __align__(16) ushort_t gw_t[2][32 * FS];      // 2 x 2.5 KB
    __shared__ __align__(16) ushort_t list_s[NSUB * SUBCAP]; // 4 KB

    const int tid = threadIdx.x;
    // center-first tile decode
    const int qb = blockIdx.x;
    const int b  = qb & 1;
    const int t_ = qb >> 1;
    const int yr = t_ / NTX, xr = t_ % NTX;
    const int yh = (yr + 1) >> 1;
    const int yb = (yr & 1) ? (16 - yh) : (16 + yh);
    const int xh = (xr + 1) >> 1;
    const int txi = (xr & 1) ? (5 - xh) : (5 + xh);
    const int tb  = (b * NYB + yb) * NTX + txi;
    const int y0 = yb * 2, x0 = txi * TW;

    // ---- gather sub-lists -> contiguous LDS list (counts prefetched) ----
    int cs[NSUB];
#pragma unroll
    for (int s = 0; s < NSUB; ++s)
        cs[s] = min(counts[(tb * NSUB + s) * CSTRIDE], SUBCAP);
    int off[NSUB];
    int tot = 0;
#pragma unroll
    for (int s = 0; s < NSUB; ++s) { off[s] = tot; tot += cs[s]; }
#pragma unroll
    for (int s = 0; s < NSUB; ++s) {
        const ushort_t* src = lists + ((size_t)tb * NSUB + s) * SUBCAP;
        if (tid < cs[s]) list_s[off[s] + tid] = src[tid];
    }
    __syncthreads();
    const int cnt = tot;

    const int gs   = tid >> 5;            // phase A gaussian sub-slot (0..15)
    const int px32 = tid & 31;            // phase A pixel (row*16+x)
    const float fy = (float)(y0 + (px32 >> 4));
    const float fx = (float)(x0 + (px32 & 15));
    const int chg = tid >> 4;             // stage: ch group (0..31), 8 ch each
    const int qp  = tid & 15;             // stage: q pair (0..15)
    const int bN = b * N_;
    const int lane = tid & 63;
    const int wv_  = tid >> 6;            // 0..7
    const int quad = lane >> 4;
    const int ln15 = lane & 15;

    f32x4 acc[2][2];
#pragma unroll
    for (int mt = 0; mt < 2; ++mt)
#pragma unroll
        for (int nt = 0; nt < 2; ++nt) acc[mt][nt] = (f32x4){0.f, 0.f, 0.f, 0.f};
    float densp = 0.f, uncp = 0.f;

    const int nchunks = (cnt + 31) >> 5;
    const float4* pv = (const float4*)pp;

    // macros over named registers (all static indexing)
#define FTB_LOAD(dstA, dstB, chunk)                                            \
    {                                                                          \
        const int q0_ = (chunk) * 32 + 2 * qp;                                 \
        const int n0_ = list_s[min(q0_, cnt - 1)];                             \
        const int n1_ = list_s[min(q0_ + 1, cnt - 1)];                         \
        dstA = *(const uint4*)(ftb + ((size_t)(bN + n0_) << 8) + chg * 8);     \
        dstB = *(const uint4*)(ftb + ((size_t)(bN + n1_) << 8) + chg * 8);     \
    }
#define PV_LOAD(chunk)                                                         \
    {                                                                          \
        _Pragma("unroll")                                                      \
        for (int jj = 0; jj < 2; ++jj) {                                       \
            const int qi_ = (chunk) * 32 + 16 * jj + gs;                       \
            const int n_ = list_s[min(qi_, cnt - 1)];                          \
            pe0[jj] = pv[(size_t)(bN + n_) * 2 + 0];                           \
            pe1[jj] = pv[(size_t)(bN + n_) * 2 + 1];                           \
        }                                                                      \
    }
#define PHASE_A(bufc, chunk)                                                   \
    {                                                                          \
        _Pragma("unroll")                                                      \
        for (int jj = 0; jj < 2; ++jj) {                                       \
            const int q = 16 * jj + gs;                                        \
            const int qi = (chunk) * 32 + q;                                   \
            const float4 e0 = pe0[jj];                                         \
            const float4 e1 = pe1[jj];                                         \
            const float dyn = (fy - e0.y) * e0.w;                              \
            const float dxn = (fx - e0.x) * e0.z;                              \
            const float dist = dyn * dyn + dxn * dxn;                          \
            float gv = 0.f;                                                    \
            if (dist < 9.f) gv = __expf(-0.5f * dist) * e1.x;                  \
            if (qi >= cnt) gv = 0.f;                                           \
            gw_t[bufc][px32 * FS + q] = (ushort_t)f2bf(gv);                    \
            densp += gv;                                                       \
            uncp  += gv * e1.y;                                                \
        }                                                                      \
    }
#define STAGE(bufc, ua, ub)                                                    \
    {                                                                          \
        uint* dst = (uint*)&feats_t[bufc][0];                                  \
        _Pragma("unroll")                                                      \
        for (int jj = 0; jj < 4; ++jj) {                                       \
            const uint u0 = (&(ua).x)[jj], v0 = (&(ub).x)[jj];                 \
            const int ch = chg * 8 + 2 * jj;                                   \
            dst[ch * (FS / 2) + qp]       = (u0 & 0xffffu) | (v0 << 16);       \
            dst[(ch + 1) * (FS / 2) + qp] = (u0 >> 16) | (v0 & 0xffff0000u);   \
        }                                                                      \
    }
#define PHASE_B(bufc)                                                          \
    {                                                                          \
        bf16x8 af0 = *(const bf16x8*)&gw_t[bufc][(ln15) * FS + quad * 8];      \
        bf16x8 af1 = *(const bf16x8*)&gw_t[bufc][(16 + ln15) * FS + quad * 8]; \
        _Pragma("unroll")                                                      \
        for (int nt = 0; nt < 2; ++nt) {                                       \
            const int ch0 = wv_ * 32 + nt * 16;                                \
            const bf16x8 bfv =                                                 \
                *(const bf16x8*)&feats_t[bufc][(ch0 + ln15) * FS + quad * 8];  \
            acc[0][nt] = __builtin_amdgcn_mfma_f32_16x16x32_bf16(af0, bfv,     \
                                                       acc[0][nt], 0, 0, 0);   \
            acc[1][nt] = __builtin_amdgcn_mfma_f32_16x16x32_bf16(af1, bfv,     \
                                                       acc[1][nt], 0, 0, 0);   \
        }                                                                      \
    }

    if (cnt > 0) {
        uint4 fa0, fb0, fa1, fb1;          // named prefetch sets (no arrays!)
        float4 pe0[2], pe1[2];             // static jj indexing only
        FTB_LOAD(fa0, fb0, 0);
        if (nchunks > 1) FTB_LOAD(fa1, fb1, 1);
        PV_LOAD(0);

        for (int c = 0; c < nchunks; c += 2) {
            // ---------- even chunk (buf 0, regs fa0/fb0) ----------
            PHASE_A(0, c);
            if (c + 1 < nchunks) PV_LOAD(c + 1);
            STAGE(0, fa0, fb0);
            __syncthreads();
            if (c + 2 < nchunks) FTB_LOAD(fa0, fb0, c + 2);   // distance 2
            PHASE_B(0);
            if (c + 1 >= nchunks) break;
            // ---------- odd chunk (buf 1, regs fa1/fb1) ----------
            PHASE_A(1, c + 1);
            if (c + 2 < nchunks) PV_LOAD(c + 2);
            STAGE(1, fa1, fb1);
            __syncthreads();
            if (c + 3 < nchunks) FTB_LOAD(fa1, fb1, c + 3);   // distance 2
            PHASE_B(1);
        }
    }
#undef FTB_LOAD
#undef PV_LOAD
#undef PHASE_A
#undef STAGE
#undef PHASE_B

    // ---- density / uncertainty reduction over 16 gs-groups ----
    __syncthreads();
    float* red_d = (float*)&feats_t[0][0];   // 16 x 36
    float* red_u = red_d + 16 * 36;
    red_d[gs * 36 + px32] = densp;
    red_u[gs * 36 + px32] = uncp;
    __syncthreads();
    for (int s = 8; s > 0; s >>= 1) {
        if (gs < s) {
            red_d[gs * 36 + px32] += red_d[(gs + s) * 36 + px32];
            red_u[gs * 36 + px32] += red_u[(gs + s) * 36 + px32];
        }
        __syncthreads();
    }

    if (tid < 32) {
        const int yy = y0 + (tid >> 4), xx = x0 + (tid & 15);
        const size_t pix = ((size_t)b * H_ + yy) * W_ + xx;
        float* unc_o = out + (size_t)B_ * C_ * H_ * W_;
        float* den_o = unc_o + (size_t)B_ * H_ * W_;
        const float d = fmaxf(red_d[tid], 1e-6f);
        unc_o[pix] = red_u[tid] / d;
        den_o[pix] = d;
    }

    // ---- feature stores: lane = ch (ln15), 4 consecutive x per acc ----
#pragma unroll
    for (int mt = 0; mt < 2; ++mt) {
        const int pxb = mt * 16 + quad * 4;
        float rinv[4];
#pragma unroll
        for (int r = 0; r < 4; ++r)
            rinv[r] = 1.f / fmaxf(red_d[pxb + r], 1e-6f);
        const int yy = y0 + mt;
#pragma unroll
        for (int nt = 0; nt < 2; ++nt) {
            const int ch = wv_ * 32 + nt * 16 + ln15;
            float4 v;
            v.x = acc[mt][nt][0] * rinv[0];
            v.y = acc[mt][nt][1] * rinv[1];
            v.z = acc[mt][nt][2] * rinv[2];
            v.w = acc[mt][nt][3] * rinv[3];
            *(float4*)(out + (((size_t)b * C_ + ch) * H_ + yy) * W_
                       + x0 + quad * 4) = v;
        }
    }
}

// ---------------------------------------------------------------------------
extern "C" void kernel_launch(void* const* d_in, const int* in_sizes, int n_in,
                              void* d_out, int out_size, void* d_ws, size_t ws_size,
                              hipStream_t stream)
{
    const float* g    = (const float*)d_in[0];
    const float* intr = (const float*)d_in[1];
    const float* w1   = (const float*)d_in[2];
    const float* b1   = (const float*)d_in[3];
    const float* w2   = (const float*)d_in[4];
    const float* b2   = (const float*)d_in[5];
    const float* w3   = (const float*)d_in[6];
    const float* b3   = (const float*)d_in[7];
    const float* fw1  = (const float*)d_in[8];
    const float* fb1  = (const float*)d_in[9];
    const float* fw2  = (const float*)d_in[10];
    const float* fb2  = (const float*)d_in[11];

    char* base = (char*)d_ws;
    const int rows = B_ * N_;                                // 4096
    ushort_t* ftb = (ushort_t*)base;                         // 2 MB bf16 [row][ch]
    float* pp     = (float*)(base + (size_t)rows * C_ * 2);  // 128 KB
    int*   counts = (int*)(pp + (size_t)8 * rows);           // 704*8 counters, 64B apart
    ushort_t* lists = (ushort_t*)(counts + NTILES2 * NSUB * CSTRIDE); // 2.9 MB
    short* wt3    = (short*)(lists + (size_t)NTILES2 * NSUB * SUBCAP);
    short* wt4    = wt3 + 128 * 256;
    short* wt5    = wt4 + 256 * 256;

    prep_kernel<<<dim3(256), dim3(256), 0, stream>>>(w3, fw1, fw2, wt3, wt4, wt5, counts);
    pb_mlp_kernel<<<dim3(512), dim3(512), 0, stream>>>(
        g, intr, w1, b1, w2, b2, wt3, b3, wt4, fb1, wt5, fb2, ftb, pp, counts, lists);
    splat_kernel<<<dim3(NTILES2), dim3(512), 0, stream>>>(pp, lists, counts, ftb, (float*)d_out);
}

// Round 8
// 129.565 us; speedup vs baseline: 1.1456x; 1.0292x over previous
//
#include <hip/hip_runtime.h>
#include <cstdint>
#include <cstddef>

#define B_ 2
#define N_ 2048
#define C_ 256
#define H_ 64
#define W_ 176
#define TW 16
#define NTX 11                    // 176/16 tiles per row
#define NYB 32                    // 2-row bands
#define NTILES2 (B_*NYB*NTX)      // 704 tiles (16px x 2row)
#define NSUB 8                    // per-tile counter/list shards
#define SUBCAP 256                // per-shard list cap
#define FS 40                     // feats_t / gw_t row stride (ushort) = 80 B
#define CSTRIDE 16                // counters padded to 1 per 64B line
#define SAB 264                   // bf16 activation LDS stride (ushorts)

typedef unsigned short ushort_t;
typedef short bf16x8 __attribute__((ext_vector_type(8)));
typedef float f32x4  __attribute__((ext_vector_type(4)));

__device__ __forceinline__ short f2bf(float f)   // RNE fp32->bf16
{
    unsigned u = __float_as_uint(f);
    return (short)((u + 0x7FFFu + ((u >> 16) & 1u)) >> 16);
}

// ---------------------------------------------------------------------------
// prep: zero tile counters + fp32->bf16 transposed weight convert.
// ---------------------------------------------------------------------------
__global__ __launch_bounds__(256)
void prep_kernel(const float* __restrict__ w3f, const float* __restrict__ fw1f,
                 const float* __restrict__ fw2f,
                 short* __restrict__ wt3, short* __restrict__ wt4,
                 short* __restrict__ wt5, int* __restrict__ counts)
{
    const int gid = blockIdx.x * 256 + threadIdx.x;
    for (int c = gid; c < NTILES2 * NSUB * CSTRIDE; c += 65536) counts[c] = 0;
    for (int e = gid; e < 163840; e += 65536) {
        if (e < 32768) {                      // w3f[k][n] (128x256) -> wt3[n*128+k]
            const int k = e >> 8, n = e & 255;
            wt3[n * 128 + k] = f2bf(w3f[e]);
        } else if (e < 98304) {               // fw1f[k][n] (256x256) -> wt4[n*256+k]
            const int e2 = e - 32768;
            const int k = e2 >> 8, n = e2 & 255;
            wt4[n * 256 + k] = f2bf(fw1f[e2]);
        } else {                              // fw2f[k][n] (256x256) -> wt5[n*256+k]
            const int e2 = e - 98304;
            const int k = e2 >> 8, n = e2 & 255;
            wt5[n * 256 + k] = f2bf(fw2f[e2]);
        }
    }
}

// ---------------------------------------------------------------------------
// MFMA accumulate on bf16 LDS activations (converted once at write time).
// ---------------------------------------------------------------------------
template<int K>
__device__ __forceinline__ void mfma_accB(const short* __restrict__ wt,
                                          const ushort_t* actB, f32x4 (&acc)[2],
                                          int wv_, int quad, int ln15)
{
    bf16x8 wreg[K / 16];
#pragma unroll
    for (int ks = 0; ks < K / 32; ++ks) {
        const int kb = ks * 32 + quad * 8;
#pragma unroll
        for (int tt = 0; tt < 2; ++tt) {
            const int n0 = (wv_ * 2 + tt) * 16;
            wreg[ks * 2 + tt] = *(const bf16x8*)&wt[(size_t)(n0 + ln15) * K + kb];
        }
    }
#pragma unroll
    for (int ks = 0; ks < K / 32; ++ks) {
        const int kb = ks * 32 + quad * 8;
        const bf16x8 af = *(const bf16x8*)&actB[ln15 * SAB + kb];
#pragma unroll
        for (int tt = 0; tt < 2; ++tt)
            acc[tt] = __builtin_amdgcn_mfma_f32_16x16x32_bf16(af, wreg[ks * 2 + tt],
                                                              acc[tt], 0, 0, 0);
    }
}

// ---------------------------------------------------------------------------
// Fused MLP + param/bin, 512 threads. Activations held bf16 in LDS.
// ---------------------------------------------------------------------------
__global__ __launch_bounds__(512, 4)
void pb_mlp_kernel(const float* __restrict__ g, const float* __restrict__ intr,
                   const float* __restrict__ w1, const float* __restrict__ b1,
                   const float* __restrict__ w2, const float* __restrict__ b2,
                   const short* __restrict__ wt3, const float* __restrict__ b3,
                   const short* __restrict__ wt4, const float* __restrict__ fb1,
                   const short* __restrict__ wt5, const float* __restrict__ fb2,
                   ushort_t* __restrict__ ftb,
                   float* __restrict__ pp, int* __restrict__ counts,
                   ushort_t* __restrict__ lists)
{
    __shared__ __align__(16) float   s32a[16 * 16];    // g input (14 cols)
    __shared__ __align__(16) float   s32b[16 * 68];    // L1 out fp32 (64 cols)
    __shared__ __align__(16) ushort_t bA[16 * SAB];    // L2 out / L4 out (bf16)
    __shared__ __align__(16) ushort_t bB[16 * SAB];    // L3 out (bf16)
    const int tid = threadIdx.x;

    if (blockIdx.x < 256) {
        const int row0 = blockIdx.x * 16;
        const int lane = tid & 63;
        const int wv_  = tid >> 6;
        const int quad = lane >> 4;
        const int ln15 = lane & 15;

        if (tid < 224) {
            const int k = tid / 16, m = tid % 16;
            s32a[m * 16 + k] = g[(size_t)(row0 + m) * 14 + k];
        }
        __syncthreads();

        {   // L1: 14 -> 64, relu (fp32 out)
            const int col = tid & 63;
            const int m0  = (tid >> 6) * 2;
            float acc[2];
            const float bv = b1[col];
            acc[0] = bv; acc[1] = bv;
#pragma unroll
            for (int k = 0; k < 14; ++k) {
                const float wv = w1[k * 64 + col];
                acc[0] = fmaf(s32a[(m0 + 0) * 16 + k], wv, acc[0]);
                acc[1] = fmaf(s32a[(m0 + 1) * 16 + k], wv, acc[1]);
            }
            s32b[(m0 + 0) * 68 + col] = fmaxf(acc[0], 0.f);
            s32b[(m0 + 1) * 68 + col] = fmaxf(acc[1], 0.f);
        }
        __syncthreads();

        {   // L2: 64 -> 128, relu -> bf16 (converted once at write)
            const int col = tid & 127;
            const int m0  = (tid >> 7) * 4;
            float acc[4];
            const float bv = b2[col];
#pragma unroll
            for (int r = 0; r < 4; ++r) acc[r] = bv;
#pragma unroll 4
            for (int kq = 0; kq < 16; ++kq) {
                float wv[4];
#pragma unroll
                for (int jj = 0; jj < 4; ++jj) wv[jj] = w2[(4 * kq + jj) * 128 + col];
#pragma unroll
                for (int r = 0; r < 4; ++r) {
                    const float4 a4 = *(const float4*)&s32b[(m0 + r) * 68 + 4 * kq];
                    acc[r] = fmaf(a4.x, wv[0], acc[r]);
                    acc[r] = fmaf(a4.y, wv[1], acc[r]);
                    acc[r] = fmaf(a4.z, wv[2], acc[r]);
                    acc[r] = fmaf(a4.w, wv[3], acc[r]);
                }
            }
#pragma unroll
            for (int r = 0; r < 4; ++r)
                bA[(m0 + r) * SAB + col] = (ushort_t)f2bf(fmaxf(acc[r], 0.f));
        }
        __syncthreads();

        {   // L3: 128 -> 256 MFMA, out -> bB (bf16)
            f32x4 acc[2] = {{0,0,0,0},{0,0,0,0}};
            mfma_accB<128>(wt3, bA, acc, wv_, quad, ln15);
#pragma unroll
            for (int tt = 0; tt < 2; ++tt) {
                const int n = (wv_ * 2 + tt) * 16 + ln15;
                const float bv = b3[n];
#pragma unroll
                for (int r = 0; r < 4; ++r)
                    bB[(quad * 4 + r) * SAB + n] = (ushort_t)f2bf(acc[tt][r] + bv);
            }
        }
        __syncthreads();

        {   // L4: 256 -> 256 MFMA, relu, out -> bA (bf16)
            f32x4 acc[2] = {{0,0,0,0},{0,0,0,0}};
            mfma_accB<256>(wt4, bB, acc, wv_, quad, ln15);
#pragma unroll
            for (int tt = 0; tt < 2; ++tt) {
                const int n = (wv_ * 2 + tt) * 16 + ln15;
                const float bv = fb1[n];
#pragma unroll
                for (int r = 0; r < 4; ++r)
                    bA[(quad * 4 + r) * SAB + n] =
                        (ushort_t)f2bf(fmaxf(acc[tt][r] + bv, 0.f));
            }
        }
        __syncthreads();

        {   // L5: 256 -> 256 MFMA -> global bf16
            f32x4 acc[2] = {{0,0,0,0},{0,0,0,0}};
            mfma_accB<256>(wt5, bA, acc, wv_, quad, ln15);
#pragma unroll
            for (int tt = 0; tt < 2; ++tt) {
                const int n = (wv_ * 2 + tt) * 16 + ln15;
                const float bv = fb2[n];
#pragma unroll
                for (int r = 0; r < 4; ++r)
                    ftb[(size_t)(row0 + quad * 4 + r) * 256 + n] =
                        (ushort_t)f2bf(acc[tt][r] + bv);
            }
        }
        return;
    }

    // ================= param + bin role (2-row bands) =================
    const int sub = (blockIdx.x - 256) & (NSUB - 1);
    const int i = (blockIdx.x - 256) * 16 + (tid >> 5);
    const int j = tid & 31;
    const float* gi = g + (size_t)i * 14;
    const float x = gi[0], y = gi[1], z = gi[2];
    const float s5 = gi[5], s6 = gi[6], wv = gi[12];
    const float k00 = intr[0], k01 = intr[1], k02 = intr[2];
    const float k10 = intr[3], k11 = intr[4], k12 = intr[5];
    const float k20 = intr[6], k21 = intr[7], k22 = intr[8];
    const float projx = k00 * x + k01 * y + k02 * z;
    const float projy = k10 * x + k11 * y + k12 * z;
    const float projz = k20 * x + k21 * y + k22 * z;
    const float inv = 1.f / (projz + 1e-6f);
    const float scale_x = (float)W_ / k02 * 0.5f;
    const float scale_y = (float)H_ / k12 * 0.5f;
    const float px = projx * inv * scale_x;
    const float py = projy * inv * scale_y;
    const bool valid = z > 0.1f;
    const bool inb = (px >= 0.f) && (px < (float)W_) && (py >= 0.f) && (py < (float)H_);
    const bool mask = valid && inb;
    const float sx = fmaxf(s5 * scale_x, 1.f);
    const float sy = fmaxf(s6 * scale_y, 1.f);
    if (j == 0) {
        float4* o = (float4*)(pp + (size_t)i * 8);
        o[0] = make_float4(px, py, 1.f / sx, 1.f / sy);
        o[1] = make_float4(wv, 0.5f * (sx + sy), 0.f, 0.f);
    }
    if (!mask) return;
    const float rx = 3.f * sx, ry = 3.f * sy;
    const int ymin = max(0, (int)floorf(py - ry));
    const int ymax = min(H_ - 1, (int)ceilf(py + ry));
    const int bmin = ymin >> 1, bmax = ymax >> 1;
    const int band = bmin + j;
    if (band > bmax) return;
    const int tmin = max(0, (int)floorf((px - rx - (float)(TW - 1)) * (1.f / TW)));
    const int tmax = min(NTX - 1, (int)ceilf((px + rx) * (1.f / TW)));
    const int b = i / N_, n = i - b * N_;
    for (int t = tmin; t <= tmax; ++t) {
        const int tile = (b * NYB + band) * NTX + t;
        const int slot = atomicAdd(&counts[(tile * NSUB + sub) * CSTRIDE], 1);
        if (slot < SUBCAP)
            lists[((size_t)tile * NSUB + sub) * SUBCAP + slot] = (ushort_t)n;
    }
}

// ---------------------------------------------------------------------------
// Splat, 512 threads / 8 waves (exact Round-5-measured structure: simple
// distance-1 ftb refill after the barrier, pv params loaded inline in phase A).
// ---------------------------------------------------------------------------
__global__ __launch_bounds__(512)
void splat_kernel(const float* __restrict__ pp, const ushort_t* __restrict__ lists,
                  const int* __restrict__ counts, const ushort_t* __restrict__ ftb,
                  float* __restrict__ out)
{
    __shared__ __align__(16) ushort_t feats_t[2][256 * FS];  // 2 x 20 KB
    __shared__ __align__(16) ushort_t gw_t[2][32 * FS];      // 2 x 2.5 KB
    __shared__ __align__(16) ushort_t list_s[NSUB * SUBCAP]; // 4 KB

    const int tid = threadIdx.x;
    // center-first tile decode
    const int qb = blockIdx.x;
    const int b  = qb & 1;
    const int t_ = qb >> 1;
    const int yr = t_ / NTX, xr = t_ % NTX;
    const int yh = (yr + 1) >> 1;
    const int yb = (yr & 1) ? (16 - yh) : (16 + yh);
    const int xh = (xr + 1) >> 1;
    const int txi = (xr & 1) ? (5 - xh) : (5 + xh);
    const int tb  = (b * NYB + yb) * NTX + txi;
    const int y0 = yb * 2, x0 = txi * TW;

    // ---- gather sub-lists -> contiguous LDS list (counts prefetched) ----
    int cs[NSUB];
#pragma unroll
    for (int s = 0; s < NSUB; ++s)
        cs[s] = min(counts[(tb * NSUB + s) * CSTRIDE], SUBCAP);
    int off[NSUB];
    int tot = 0;
#pragma unroll
    for (int s = 0; s < NSUB; ++s) { off[s] = tot; tot += cs[s]; }
#pragma unroll
    for (int s = 0; s < NSUB; ++s) {
        const ushort_t* src = lists + ((size_t)tb * NSUB + s) * SUBCAP;
        if (tid < cs[s]) list_s[off[s] + tid] = src[tid];
    }
    __syncthreads();
    const int cnt = tot;

    const ushort_t* mylist = list_s;
    const int gs   = tid >> 5;            // phase A gaussian sub-slot (0..15)
    const int px32 = tid & 31;            // phase A pixel (row*16+x)
    const float fy = (float)(y0 + (px32 >> 4));
    const float fx = (float)(x0 + (px32 & 15));
    const int chg = tid >> 4;             // stage: ch group (0..31), 8 ch each
    const int qp  = tid & 15;             // stage: q pair (0..15)
    const int bN = b * N_;
    const int lane = tid & 63;
    const int wv_  = tid >> 6;            // 0..7
    const int quad = lane >> 4;
    const int ln15 = lane & 15;

    f32x4 acc[2][2];
#pragma unroll
    for (int mt = 0; mt < 2; ++mt)
#pragma unroll
        for (int nt = 0; nt < 2; ++nt) acc[mt][nt] = (f32x4){0.f, 0.f, 0.f, 0.f};
    float densp = 0.f, uncp = 0.f;

    uint4 ra0, rb0;                       // staged 8ch x 2 rows
    const int nchunks = (cnt + 31) >> 5;

    if (cnt > 0) {
        const float4* pv = (const float4*)pp;
        {   // prefetch chunk 0 rows
            const int n0 = mylist[min(2 * qp, cnt - 1)];
            const int n1 = mylist[min(2 * qp + 1, cnt - 1)];
            ra0 = *(const uint4*)(ftb + ((size_t)(bN + n0) << 8) + chg * 8);
            rb0 = *(const uint4*)(ftb + ((size_t)(bN + n1) << 8) + chg * 8);
        }
        for (int c = 0; c < nchunks; ++c) {
            const int buf = c & 1;
            // ---- phase A: 2 gw per thread -> gw_t[buf] (bf16) ----
#pragma unroll
            for (int jj = 0; jj < 2; ++jj) {
                const int q = 16 * jj + gs;
                const int qi = c * 32 + q;
                const int n = mylist[min(qi, cnt - 1)];
                const float4 e0 = pv[(size_t)(bN + n) * 2 + 0];
                const float4 e1 = pv[(size_t)(bN + n) * 2 + 1];
                const float dyn = (fy - e0.y) * e0.w;
                const float dxn = (fx - e0.x) * e0.z;
                const float dist = dyn * dyn + dxn * dxn;
                float gv = 0.f;
                if (dist < 9.f) gv = __expf(-0.5f * dist) * e1.x;
                if (qi >= cnt) gv = 0.f;
                gw_t[buf][px32 * FS + q] = (ushort_t)f2bf(gv);
                densp += gv;
                uncp  += gv * e1.y;
            }
            // ---- stage: transpose regs -> feats_t[buf][ch][k] ----
            {
                uint* dst = (uint*)&feats_t[buf][0];
#pragma unroll
                for (int jj = 0; jj < 4; ++jj) {
                    const uint u0 = (&ra0.x)[jj], v0 = (&rb0.x)[jj];
                    const int ch = chg * 8 + 2 * jj;
                    dst[ch * (FS / 2) + qp]       = (u0 & 0xffffu) | (v0 << 16);
                    dst[(ch + 1) * (FS / 2) + qp] = (u0 >> 16) | (v0 & 0xffff0000u);
                }
            }
            __syncthreads();
            // ---- prefetch chunk c+1 rows (overlaps phase B) ----
            if (c + 1 < nchunks) {
                const int q0 = (c + 1) * 32 + 2 * qp;
                const int n0 = mylist[min(q0, cnt - 1)];
                const int n1 = mylist[min(q0 + 1, cnt - 1)];
                ra0 = *(const uint4*)(ftb + ((size_t)(bN + n0) << 8) + chg * 8);
                rb0 = *(const uint4*)(ftb + ((size_t)(bN + n1) << 8) + chg * 8);
            }
            // ---- phase B: 4 MFMA per wave ----
            bf16x8 af[2];
#pragma unroll
            for (int mt = 0; mt < 2; ++mt)
                af[mt] = *(const bf16x8*)&gw_t[buf][(mt * 16 + ln15) * FS + quad * 8];
#pragma unroll
            for (int nt = 0; nt < 2; ++nt) {
                const int ch0 = wv_ * 32 + nt * 16;
                const bf16x8 bf = *(const bf16x8*)&feats_t[buf][(ch0 + ln15) * FS + quad * 8];
                acc[0][nt] = __builtin_amdgcn_mfma_f32_16x16x32_bf16(af[0], bf, acc[0][nt], 0, 0, 0);
                acc[1][nt] = __builtin_amdgcn_mfma_f32_16x16x32_bf16(af[1], bf, acc[1][nt], 0, 0, 0);
            }
        }
    }

    // ---- density / uncertainty reduction over 16 gs-groups ----
    __syncthreads();
    float* red_d = (float*)&feats_t[0][0];   // 16 x 36
    float* red_u = red_d + 16 * 36;
    red_d[gs * 36 + px32] = densp;
    red_u[gs * 36 + px32] = uncp;
    __syncthreads();
    for (int s = 8; s > 0; s >>= 1) {
        if (gs < s) {
            red_d[gs * 36 + px32] += red_d[(gs + s) * 36 + px32];
            red_u[gs * 36 + px32] += red_u[(gs + s) * 36 + px32];
        }
        __syncthreads();
    }

    if (tid < 32) {
        const int yy = y0 + (tid >> 4), xx = x0 + (tid & 15);
        const size_t pix = ((size_t)b * H_ + yy) * W_ + xx;
        float* unc_o = out + (size_t)B_ * C_ * H_ * W_;
        float* den_o = unc_o + (size_t)B_ * H_ * W_;
        const float d = fmaxf(red_d[tid], 1e-6f);
        unc_o[pix] = red_u[tid] / d;
        den_o[pix] = d;
    }

    // ---- feature stores: lane = ch (ln15), 4 consecutive x per acc ----
#pragma unroll
    for (int mt = 0; mt < 2; ++mt) {
        const int pxb = mt * 16 + quad * 4;
        float rinv[4];
#pragma unroll
        for (int r = 0; r < 4; ++r)
            rinv[r] = 1.f / fmaxf(red_d[pxb + r], 1e-6f);
        const int yy = y0 + mt;
#pragma unroll
        for (int nt = 0; nt < 2; ++nt) {
            const int ch = wv_ * 32 + nt * 16 + ln15;
            float4 v;
            v.x = acc[mt][nt][0] * rinv[0];
            v.y = acc[mt][nt][1] * rinv[1];
            v.z = acc[mt][nt][2] * rinv[2];
            v.w = acc[mt][nt][3] * rinv[3];
            *(float4*)(out + (((size_t)b * C_ + ch) * H_ + yy) * W_
                       + x0 + quad * 4) = v;
        }
    }
}

// ---------------------------------------------------------------------------
extern "C" void kernel_launch(void* const* d_in, const int* in_sizes, int n_in,
                              void* d_out, int out_size, void* d_ws, size_t ws_size,
                              hipStream_t stream)
{
    const float* g    = (const float*)d_in[0];
    const float* intr = (const float*)d_in[1];
    const float* w1   = (const float*)d_in[2];
    const float* b1   = (const float*)d_in[3];
    const float* w2   = (const float*)d_in[4];
    const float* b2   = (const float*)d_in[5];
    const float* w3   = (const float*)d_in[6];
    const float* b3   = (const float*)d_in[7];
    const float* fw1  = (const float*)d_in[8];
    const float* fb1  = (const float*)d_in[9];
    const float* fw2  = (const float*)d_in[10];
    const float* fb2  = (const float*)d_in[11];

    char* base = (char*)d_ws;
    const int rows = B_ * N_;                                // 4096
    ushort_t* ftb = (ushort_t*)base;                         // 2 MB bf16 [row][ch]
    float* pp     = (float*)(base + (size_t)rows * C_ * 2);  // 128 KB
    int*   counts = (int*)(pp + (size_t)8 * rows);           // 704*8 counters, 64B apart
    ushort_t* lists = (ushort_t*)(counts + NTILES2 * NSUB * CSTRIDE); // 2.9 MB
    short* wt3    = (short*)(lists + (size_t)NTILES2 * NSUB * SUBCAP);
    short* wt4    = wt3 + 128 * 256;
    short* wt5    = wt4 + 256 * 256;

    prep_kernel<<<dim3(256), dim3(256), 0, stream>>>(w3, fw1, fw2, wt3, wt4, wt5, counts);
    pb_mlp_kernel<<<dim3(512), dim3(512), 0, stream>>>(
        g, intr, w1, b1, w2, b2, wt3, b3, wt4, fb1, wt5, fb2, ftb, pp, counts, lists);
    splat_kernel<<<dim3(NTILES2), dim3(512), 0, stream>>>(pp, lists, counts, ftb, (float*)d_out);
}

// Round 9
// 128.347 us; speedup vs baseline: 1.1565x; 1.0095x over previous
//
#include <hip/hip_runtime.h>
#include <cstdint>
#include <cstddef>

#define B_ 2
#define N_ 2048
#define C_ 256
#define H_ 64
#define W_ 176
#define TW 16
#define NTX 11                    // 176/16 tiles per row
#define NYB 32                    // 2-row bands
#define NTILES2 (B_*NYB*NTX)      // 704 tiles (16px x 2row)
#define NSUB 8                    // per-tile counter/list shards
#define SUBCAP 256                // per-shard list cap
#define FS 40                     // feats_t / gw_t row stride (ushort) = 80 B
#define CSTRIDE 16                // counters padded to 1 per 64B line
#define SAB 264                   // bf16 activation LDS stride (ushorts)

typedef unsigned short ushort_t;
typedef short bf16x8 __attribute__((ext_vector_type(8)));
typedef float f32x4  __attribute__((ext_vector_type(4)));

__device__ __forceinline__ short f2bf(float f)   // RNE fp32->bf16
{
    unsigned u = __float_as_uint(f);
    return (short)((u + 0x7FFFu + ((u >> 16) & 1u)) >> 16);
}

// ---------------------------------------------------------------------------
// MFMA accumulate reading fp32 weights DIRECTLY from global (row stride 256),
// converting to bf16 at preload. Bit-identical to the old prep->wt path:
// wreg[j] = f2bf(wf[(kb+j)*256 + n]). 8 quad-coalesced dword loads/fragment.
// Activations are bf16 in LDS (converted once at write time).
// ---------------------------------------------------------------------------
template<int K>
__device__ __forceinline__ void mfma_accF(const float* __restrict__ wf,
                                          const ushort_t* actB, f32x4 (&acc)[2],
                                          int wv_, int quad, int ln15)
{
    bf16x8 wreg[K / 16];
#pragma unroll
    for (int ks = 0; ks < K / 32; ++ks) {
        const int kb = ks * 32 + quad * 8;
#pragma unroll
        for (int tt = 0; tt < 2; ++tt) {
            const int n = (wv_ * 2 + tt) * 16 + ln15;
            const float* src = wf + (size_t)kb * 256 + n;
            float f0 = src[0 * 256], f1 = src[1 * 256], f2 = src[2 * 256],
                  f3 = src[3 * 256], f4 = src[4 * 256], f5 = src[5 * 256],
                  f6 = src[6 * 256], f7 = src[7 * 256];
            wreg[ks * 2 + tt] = (bf16x8){ f2bf(f0), f2bf(f1), f2bf(f2), f2bf(f3),
                                          f2bf(f4), f2bf(f5), f2bf(f6), f2bf(f7) };
        }
    }
#pragma unroll
    for (int ks = 0; ks < K / 32; ++ks) {
        const int kb = ks * 32 + quad * 8;
        const bf16x8 af = *(const bf16x8*)&actB[ln15 * SAB + kb];
#pragma unroll
        for (int tt = 0; tt < 2; ++tt)
            acc[tt] = __builtin_amdgcn_mfma_f32_16x16x32_bf16(af, wreg[ks * 2 + tt],
                                                              acc[tt], 0, 0, 0);
    }
}

// ---------------------------------------------------------------------------
// Fused MLP + param/bin, 512 threads. Activations held bf16 in LDS.
// Weights read fp32 directly (no prep kernel).
// ---------------------------------------------------------------------------
__global__ __launch_bounds__(512, 4)
void pb_mlp_kernel(const float* __restrict__ g, const float* __restrict__ intr,
                   const float* __restrict__ w1, const float* __restrict__ b1,
                   const float* __restrict__ w2, const float* __restrict__ b2,
                   const float* __restrict__ w3f, const float* __restrict__ b3,
                   const float* __restrict__ fw1f, const float* __restrict__ fb1,
                   const float* __restrict__ fw2f, const float* __restrict__ fb2,
                   ushort_t* __restrict__ ftb,
                   float* __restrict__ pp, int* __restrict__ counts,
                   ushort_t* __restrict__ lists)
{
    __shared__ __align__(16) float   s32a[16 * 16];    // g input (14 cols)
    __shared__ __align__(16) float   s32b[16 * 68];    // L1 out fp32 (64 cols)
    __shared__ __align__(16) ushort_t bA[16 * SAB];    // L2 out / L4 out (bf16)
    __shared__ __align__(16) ushort_t bB[16 * SAB];    // L3 out (bf16)
    const int tid = threadIdx.x;

    if (blockIdx.x < 256) {
        const int row0 = blockIdx.x * 16;
        const int lane = tid & 63;
        const int wv_  = tid >> 6;
        const int quad = lane >> 4;
        const int ln15 = lane & 15;

        if (tid < 224) {
            const int k = tid / 16, m = tid % 16;
            s32a[m * 16 + k] = g[(size_t)(row0 + m) * 14 + k];
        }
        __syncthreads();

        {   // L1: 14 -> 64, relu (fp32 out)
            const int col = tid & 63;
            const int m0  = (tid >> 6) * 2;
            float acc[2];
            const float bv = b1[col];
            acc[0] = bv; acc[1] = bv;
#pragma unroll
            for (int k = 0; k < 14; ++k) {
                const float wv = w1[k * 64 + col];
                acc[0] = fmaf(s32a[(m0 + 0) * 16 + k], wv, acc[0]);
                acc[1] = fmaf(s32a[(m0 + 1) * 16 + k], wv, acc[1]);
            }
            s32b[(m0 + 0) * 68 + col] = fmaxf(acc[0], 0.f);
            s32b[(m0 + 1) * 68 + col] = fmaxf(acc[1], 0.f);
        }
        __syncthreads();

        {   // L2: 64 -> 128, relu -> bf16 (converted once at write)
            const int col = tid & 127;
            const int m0  = (tid >> 7) * 4;
            float acc[4];
            const float bv = b2[col];
#pragma unroll
            for (int r = 0; r < 4; ++r) acc[r] = bv;
#pragma unroll 4
            for (int kq = 0; kq < 16; ++kq) {
                float wv[4];
#pragma unroll
                for (int jj = 0; jj < 4; ++jj) wv[jj] = w2[(4 * kq + jj) * 128 + col];
#pragma unroll
                for (int r = 0; r < 4; ++r) {
                    const float4 a4 = *(const float4*)&s32b[(m0 + r) * 68 + 4 * kq];
                    acc[r] = fmaf(a4.x, wv[0], acc[r]);
                    acc[r] = fmaf(a4.y, wv[1], acc[r]);
                    acc[r] = fmaf(a4.z, wv[2], acc[r]);
                    acc[r] = fmaf(a4.w, wv[3], acc[r]);
                }
            }
#pragma unroll
            for (int r = 0; r < 4; ++r)
                bA[(m0 + r) * SAB + col] = (ushort_t)f2bf(fmaxf(acc[r], 0.f));
        }
        __syncthreads();

        {   // L3: 128 -> 256 MFMA, out -> bB (bf16)
            f32x4 acc[2] = {{0,0,0,0},{0,0,0,0}};
            mfma_accF<128>(w3f, bA, acc, wv_, quad, ln15);
#pragma unroll
            for (int tt = 0; tt < 2; ++tt) {
                const int n = (wv_ * 2 + tt) * 16 + ln15;
                const float bv = b3[n];
#pragma unroll
                for (int r = 0; r < 4; ++r)
                    bB[(quad * 4 + r) * SAB + n] = (ushort_t)f2bf(acc[tt][r] + bv);
            }
        }
        __syncthreads();

        {   // L4: 256 -> 256 MFMA, relu, out -> bA (bf16)
            f32x4 acc[2] = {{0,0,0,0},{0,0,0,0}};
            mfma_accF<256>(fw1f, bB, acc, wv_, quad, ln15);
#pragma unroll
            for (int tt = 0; tt < 2; ++tt) {
                const int n = (wv_ * 2 + tt) * 16 + ln15;
                const float bv = fb1[n];
#pragma unroll
                for (int r = 0; r < 4; ++r)
                    bA[(quad * 4 + r) * SAB + n] =
                        (ushort_t)f2bf(fmaxf(acc[tt][r] + bv, 0.f));
            }
        }
        __syncthreads();

        {   // L5: 256 -> 256 MFMA -> global bf16
            f32x4 acc[2] = {{0,0,0,0},{0,0,0,0}};
            mfma_accF<256>(fw2f, bA, acc, wv_, quad, ln15);
#pragma unroll
            for (int tt = 0; tt < 2; ++tt) {
                const int n = (wv_ * 2 + tt) * 16 + ln15;
                const float bv = fb2[n];
#pragma unroll
                for (int r = 0; r < 4; ++r)
                    ftb[(size_t)(row0 + quad * 4 + r) * 256 + n] =
                        (ushort_t)f2bf(acc[tt][r] + bv);
            }
        }
        return;
    }

    // ================= param + bin role (2-row bands) =================
    const int sub = (blockIdx.x - 256) & (NSUB - 1);
    const int i = (blockIdx.x - 256) * 16 + (tid >> 5);
    const int j = tid & 31;
    const float* gi = g + (size_t)i * 14;
    const float x = gi[0], y = gi[1], z = gi[2];
    const float s5 = gi[5], s6 = gi[6], wv = gi[12];
    const float k00 = intr[0], k01 = intr[1], k02 = intr[2];
    const float k10 = intr[3], k11 = intr[4], k12 = intr[5];
    const float k20 = intr[6], k21 = intr[7], k22 = intr[8];
    const float projx = k00 * x + k01 * y + k02 * z;
    const float projy = k10 * x + k11 * y + k12 * z;
    const float projz = k20 * x + k21 * y + k22 * z;
    const float inv = 1.f / (projz + 1e-6f);
    const float scale_x = (float)W_ / k02 * 0.5f;
    const float scale_y = (float)H_ / k12 * 0.5f;
    const float px = projx * inv * scale_x;
    const float py = projy * inv * scale_y;
    const bool valid = z > 0.1f;
    const bool inb = (px >= 0.f) && (px < (float)W_) && (py >= 0.f) && (py < (float)H_);
    const bool mask = valid && inb;
    const float sx = fmaxf(s5 * scale_x, 1.f);
    const float sy = fmaxf(s6 * scale_y, 1.f);
    if (j == 0) {
        float4* o = (float4*)(pp + (size_t)i * 8);
        o[0] = make_float4(px, py, 1.f / sx, 1.f / sy);
        o[1] = make_float4(wv, 0.5f * (sx + sy), 0.f, 0.f);
    }
    if (!mask) return;
    const float rx = 3.f * sx, ry = 3.f * sy;
    const int ymin = max(0, (int)floorf(py - ry));
    const int ymax = min(H_ - 1, (int)ceilf(py + ry));
    const int bmin = ymin >> 1, bmax = ymax >> 1;
    const int band = bmin + j;
    if (band > bmax) return;
    const int tmin = max(0, (int)floorf((px - rx - (float)(TW - 1)) * (1.f / TW)));
    const int tmax = min(NTX - 1, (int)ceilf((px + rx) * (1.f / TW)));
    const int b = i / N_, n = i - b * N_;
    for (int t = tmin; t <= tmax; ++t) {
        const int tile = (b * NYB + band) * NTX + t;
        const int slot = atomicAdd(&counts[(tile * NSUB + sub) * CSTRIDE], 1);
        if (slot < SUBCAP)
            lists[((size_t)tile * NSUB + sub) * SUBCAP + slot] = (ushort_t)n;
    }
}

// ---------------------------------------------------------------------------
// Splat, 512 threads / 8 waves (R5/R8-measured structure: simple distance-1
// ftb refill after the barrier, pv params loaded inline in phase A).
// ---------------------------------------------------------------------------
__global__ __launch_bounds__(512)
void splat_kernel(const float* __restrict__ pp, const ushort_t* __restrict__ lists,
                  const int* __restrict__ counts, const ushort_t* __restrict__ ftb,
                  float* __restrict__ out)
{
    __shared__ __align__(16) ushort_t feats_t[2][256 * FS];  // 2 x 20 KB
    __shared__ __align__(16) ushort_t gw_t[2][32 * FS];      // 2 x 2.5 KB
    __shared__ __align__(16) ushort_t list_s[NSUB * SUBCAP]; // 4 KB

    const int tid = threadIdx.x;
    // center-first tile decode
    const int qb = blockIdx.x;
    const int b  = qb & 1;
    const int t_ = qb >> 1;
    const int yr = t_ / NTX, xr = t_ % NTX;
    const int yh = (yr + 1) >> 1;
    const int yb = (yr & 1) ? (16 - yh) : (16 + yh);
    const int xh = (xr + 1) >> 1;
    const int txi = (xr & 1) ? (5 - xh) : (5 + xh);
    const int tb  = (b * NYB + yb) * NTX + txi;
    const int y0 = yb * 2, x0 = txi * TW;

    // ---- gather sub-lists -> contiguous LDS list (counts prefetched) ----
    int cs[NSUB];
#pragma unroll
    for (int s = 0; s < NSUB; ++s)
        cs[s] = min(counts[(tb * NSUB + s) * CSTRIDE], SUBCAP);
    int off[NSUB];
    int tot = 0;
#pragma unroll
    for (int s = 0; s < NSUB; ++s) { off[s] = tot; tot += cs[s]; }
#pragma unroll
    for (int s = 0; s < NSUB; ++s) {
        const ushort_t* src = lists + ((size_t)tb * NSUB + s) * SUBCAP;
        if (tid < cs[s]) list_s[off[s] + tid] = src[tid];
    }
    __syncthreads();
    const int cnt = tot;

    const ushort_t* mylist = list_s;
    const int gs   = tid >> 5;            // phase A gaussian sub-slot (0..15)
    const int px32 = tid & 31;            // phase A pixel (row*16+x)
    const float fy = (float)(y0 + (px32 >> 4));
    const float fx = (float)(x0 + (px32 & 15));
    const int chg = tid >> 4;             // stage: ch group (0..31), 8 ch each
    const int qp  = tid & 15;             // stage: q pair (0..15)
    const int bN = b * N_;
    const int lane = tid & 63;
    const int wv_  = tid >> 6;            // 0..7
    const int quad = lane >> 4;
    const int ln15 = lane & 15;

    f32x4 acc[2][2];
#pragma unroll
    for (int mt = 0; mt < 2; ++mt)
#pragma unroll
        for (int nt = 0; nt < 2; ++nt) acc[mt][nt] = (f32x4){0.f, 0.f, 0.f, 0.f};
    float densp = 0.f, uncp = 0.f;

    uint4 ra0, rb0;                       // staged 8ch x 2 rows
    const int nchunks = (cnt + 31) >> 5;

    if (cnt > 0) {
        const float4* pv = (const float4*)pp;
        {   // prefetch chunk 0 rows
            const int n0 = mylist[min(2 * qp, cnt - 1)];
            const int n1 = mylist[min(2 * qp + 1, cnt - 1)];
            ra0 = *(const uint4*)(ftb + ((size_t)(bN + n0) << 8) + chg * 8);
            rb0 = *(const uint4*)(ftb + ((size_t)(bN + n1) << 8) + chg * 8);
        }
        for (int c = 0; c < nchunks; ++c) {
            const int buf = c & 1;
            // ---- phase A: 2 gw per thread -> gw_t[buf] (bf16) ----
#pragma unroll
            for (int jj = 0; jj < 2; ++jj) {
                const int q = 16 * jj + gs;
                const int qi = c * 32 + q;
                const int n = mylist[min(qi, cnt - 1)];
                const float4 e0 = pv[(size_t)(bN + n) * 2 + 0];
                const float4 e1 = pv[(size_t)(bN + n) * 2 + 1];
                const float dyn = (fy - e0.y) * e0.w;
                const float dxn = (fx - e0.x) * e0.z;
                const float dist = dyn * dyn + dxn * dxn;
                float gv = 0.f;
                if (dist < 9.f) gv = __expf(-0.5f * dist) * e1.x;
                if (qi >= cnt) gv = 0.f;
                gw_t[buf][px32 * FS + q] = (ushort_t)f2bf(gv);
                densp += gv;
                uncp  += gv * e1.y;
            }
            // ---- stage: transpose regs -> feats_t[buf][ch][k] ----
            {
                uint* dst = (uint*)&feats_t[buf][0];
#pragma unroll
                for (int jj = 0; jj < 4; ++jj) {
                    const uint u0 = (&ra0.x)[jj], v0 = (&rb0.x)[jj];
                    const int ch = chg * 8 + 2 * jj;
                    dst[ch * (FS / 2) + qp]       = (u0 & 0xffffu) | (v0 << 16);
                    dst[(ch + 1) * (FS / 2) + qp] = (u0 >> 16) | (v0 & 0xffff0000u);
                }
            }
            __syncthreads();
            // ---- prefetch chunk c+1 rows (overlaps phase B) ----
            if (c + 1 < nchunks) {
                const int q0 = (c + 1) * 32 + 2 * qp;
                const int n0 = mylist[min(q0, cnt - 1)];
                const int n1 = mylist[min(q0 + 1, cnt - 1)];
                ra0 = *(const uint4*)(ftb + ((size_t)(bN + n0) << 8) + chg * 8);
                rb0 = *(const uint4*)(ftb + ((size_t)(bN + n1) << 8) + chg * 8);
            }
            // ---- phase B: 4 MFMA per wave ----
            bf16x8 af[2];
#pragma unroll
            for (int mt = 0; mt < 2; ++mt)
                af[mt] = *(const bf16x8*)&gw_t[buf][(mt * 16 + ln15) * FS + quad * 8];
#pragma unroll
            for (int nt = 0; nt < 2; ++nt) {
                const int ch0 = wv_ * 32 + nt * 16;
                const bf16x8 bf = *(const bf16x8*)&feats_t[buf][(ch0 + ln15) * FS + quad * 8];
                acc[0][nt] = __builtin_amdgcn_mfma_f32_16x16x32_bf16(af[0], bf, acc[0][nt], 0, 0, 0);
                acc[1][nt] = __builtin_amdgcn_mfma_f32_16x16x32_bf16(af[1], bf, acc[1][nt], 0, 0, 0);
            }
        }
    }

    // ---- density / uncertainty reduction over 16 gs-groups ----
    __syncthreads();
    float* red_d = (float*)&feats_t[0][0];   // 16 x 36
    float* red_u = red_d + 16 * 36;
    red_d[gs * 36 + px32] = densp;
    red_u[gs * 36 + px32] = uncp;
    __syncthreads();
    for (int s = 8; s > 0; s >>= 1) {
        if (gs < s) {
            red_d[gs * 36 + px32] += red_d[(gs + s) * 36 + px32];
            red_u[gs * 36 + px32] += red_u[(gs + s) * 36 + px32];
        }
        __syncthreads();
    }

    if (tid < 32) {
        const int yy = y0 + (tid >> 4), xx = x0 + (tid & 15);
        const size_t pix = ((size_t)b * H_ + yy) * W_ + xx;
        float* unc_o = out + (size_t)B_ * C_ * H_ * W_;
        float* den_o = unc_o + (size_t)B_ * H_ * W_;
        const float d = fmaxf(red_d[tid], 1e-6f);
        unc_o[pix] = red_u[tid] / d;
        den_o[pix] = d;
    }

    // ---- feature stores: lane = ch (ln15), 4 consecutive x per acc ----
#pragma unroll
    for (int mt = 0; mt < 2; ++mt) {
        const int pxb = mt * 16 + quad * 4;
        float rinv[4];
#pragma unroll
        for (int r = 0; r < 4; ++r)
            rinv[r] = 1.f / fmaxf(red_d[pxb + r], 1e-6f);
        const int yy = y0 + mt;
#pragma unroll
        for (int nt = 0; nt < 2; ++nt) {
            const int ch = wv_ * 32 + nt * 16 + ln15;
            float4 v;
            v.x = acc[mt][nt][0] * rinv[0];
            v.y = acc[mt][nt][1] * rinv[1];
            v.z = acc[mt][nt][2] * rinv[2];
            v.w = acc[mt][nt][3] * rinv[3];
            *(float4*)(out + (((size_t)b * C_ + ch) * H_ + yy) * W_
                       + x0 + quad * 4) = v;
        }
    }
}

// ---------------------------------------------------------------------------
extern "C" void kernel_launch(void* const* d_in, const int* in_sizes, int n_in,
                              void* d_out, int out_size, void* d_ws, size_t ws_size,
                              hipStream_t stream)
{
    const float* g    = (const float*)d_in[0];
    const float* intr = (const float*)d_in[1];
    const float* w1   = (const float*)d_in[2];
    const float* b1   = (const float*)d_in[3];
    const float* w2   = (const float*)d_in[4];
    const float* b2   = (const float*)d_in[5];
    const float* w3   = (const float*)d_in[6];
    const float* b3   = (const float*)d_in[7];
    const float* fw1  = (const float*)d_in[8];
    const float* fb1  = (const float*)d_in[9];
    const float* fw2  = (const float*)d_in[10];
    const float* fb2  = (const float*)d_in[11];

    char* base = (char*)d_ws;
    const int rows = B_ * N_;                                // 4096
    ushort_t* ftb = (ushort_t*)base;                         // 2 MB bf16 [row][ch]
    float* pp     = (float*)(base + (size_t)rows * C_ * 2);  // 128 KB
    int*   counts = (int*)(pp + (size_t)8 * rows);           // 704*8 counters, 64B apart
    ushort_t* lists = (ushort_t*)(counts + NTILES2 * NSUB * CSTRIDE); // 2.9 MB

    // counts zeroing: tiny async fill replaces the prep kernel entirely
    hipMemsetAsync(counts, 0, (size_t)NTILES2 * NSUB * CSTRIDE * sizeof(int), stream);
    pb_mlp_kernel<<<dim3(512), dim3(512), 0, stream>>>(
        g, intr, w1, b1, w2, b2, w3, b3, fw1, fb1, fw2, fb2, ftb, pp, counts, lists);
    splat_kernel<<<dim3(NTILES2), dim3(512), 0, stream>>>(pp, lists, counts, ftb, (float*)d_out);
}